// Round 5
// baseline (38.827 us; speedup 1.0000x reference)
//
#include <hip/hip_runtime.h>

namespace {

typedef float f32x4 __attribute__((ext_vector_type(4)));

constexpr int G     = 76;
constexpr int NA    = 3;
constexpr int NC    = 85;              // 5 + 80 channels per anchor
constexpr int GG    = G * G;           // 5776
constexpr int JV    = G / 4;           // 19 float4 per channel row
constexpr int ROWF  = NC * G;          // 6460 floats per tile (one grid-row)
constexpr int ROWV  = ROWF / 4;        // 1615 float4
constexpr int NT    = 512;
constexpr int NIT   = (ROWV + NT - 1) / NT;   // 4 (last: tid<79)
constexpr int NBLK  = 16 * NA * G;     // 3648 blocks, one grid-row each

__device__ __forceinline__ float sigmoidf(float v) {
    return __builtin_amdgcn_rcpf(1.0f + __expf(-v));
}

__global__ __launch_bounds__(NT)
void yolo_decode(const float* __restrict__ x,
                 const float* __restrict__ anchors,
                 const int* __restrict__ img_dim,
                 float* __restrict__ out)
{
    __shared__ alignas(16) float lds[ROWF];   // 25,840 B -> 4 blocks/CU (thread-cap)

    const int tid = threadIdx.x;
    const int blk = blockIdx.x;
    const int i   = blk % G;               // grid row
    const int a   = (blk / G) % NA;        // anchor
    const int b   = blk / (G * NA);        // batch

    const float stride_f = (float)(*img_dim) / (float)G;   // 8
    const float aw = anchors[2 * a + 0];   // (anchor/stride)*stride cancels
    const float ah = anchors[2 * a + 1];
    const float fi = (float)i;

    const float* __restrict__ xin =
        x + (size_t)(b * (NA * NC) + a * NC) * GG + (size_t)i * G;

    // Phase A: issue ALL global loads first (max outstanding vmcnt).
    f32x4 v[NIT];
    int cmap[NIT], jmap[NIT];
    bool vmap[NIT];
    #pragma unroll
    for (int it = 0; it < NIT; ++it) {
        const int k4 = it * NT + tid;
        vmap[it] = (k4 < ROWV);
        cmap[it] = k4 / JV;
        jmap[it] = k4 - cmap[it] * JV;
        if (vmap[it])
            v[it] = *reinterpret_cast<const f32x4*>(
                xin + (size_t)cmap[it] * GG + (size_t)jmap[it] * 4);
    }

    // Phase B: transform + transpose-scatter into LDS as [j][c].
    #pragma unroll
    for (int it = 0; it < NIT; ++it) {
        if (vmap[it]) {
            const int c = cmap[it];
            #pragma unroll
            for (int e = 0; e < 4; ++e) {
                const int j = jmap[it] * 4 + e;
                const float val = v[it][e];
                float rr;
                if (c == 0)      rr = (sigmoidf(val) + (float)j) * stride_f;
                else if (c == 1) rr = (sigmoidf(val) + fi) * stride_f;
                else if (c == 2) rr = __expf(val) * aw;
                else if (c == 3) rr = __expf(val) * ah;
                else             rr = sigmoidf(val);
                lds[j * NC + c] = rr;
            }
        }
    }
    __syncthreads();

    // Phase C: 25,840 contiguous bytes per block, nontemporal float4 stores.
    float* __restrict__ outp =
        out + (size_t)((b * NA + a) * GG + i * G) * NC;
    const f32x4* __restrict__ l4 = reinterpret_cast<const f32x4*>(lds);
    f32x4* __restrict__ o4p = reinterpret_cast<f32x4*>(outp);
    #pragma unroll
    for (int it = 0; it < NIT; ++it) {
        const int o4 = it * NT + tid;
        if (o4 < ROWV)
            __builtin_nontemporal_store(l4[o4], o4p + o4);
    }
}

} // namespace

extern "C" void kernel_launch(void* const* d_in, const int* in_sizes, int n_in,
                              void* d_out, int out_size, void* d_ws, size_t ws_size,
                              hipStream_t stream) {
    const float* x       = (const float*)d_in[0];
    const float* anchors = (const float*)d_in[1];
    const int*   img_dim = (const int*)d_in[2];
    float* outp = (float*)d_out;

    yolo_decode<<<NBLK, NT, 0, stream>>>(x, anchors, img_dim, outp);
}